// Round 4
// baseline (104.011 us; speedup 1.0000x reference)
//
#include <hip/hip_runtime.h>
#include <math.h>

#define B_N 524288
#define C_N 40
constexpr int BLOCK  = 320;   // 5 waves; 320*4 = 1280 floats = 32 rows of C=40
constexpr int VEC    = 4;
constexpr int UNROLL = 2;     // 2 float4-pairs per iteration
constexpr int GRID   = 2048;  // 6 blocks co-resident/CU (30/32 waves)
constexpr int ITERS  = 4;     // 2048*2560*4 = 524288*40 exactly
constexpr int NREP   = 32;    // accumulator replicas to spread atomic contention

// Fused pass; software-pipelined: next iteration's loads issue BEFORE current
// compute, so each wave keeps >=4KB in flight instead of stalling at s_waitcnt.
// Tile stride 2560 == 0 mod 40 -> per-thread classes invariant across iters.
__global__ __launch_bounds__(BLOCK) void bdl_accum(
    const float* __restrict__ pred, const float* __restrict__ tgt,
    float* __restrict__ gacc)
{
    constexpr float LN9 = 2.1972245773362196f;
    constexpr size_t TILE   = (size_t)BLOCK * VEC * UNROLL;  // 2560
    constexpr size_t STRIDE = (size_t)GRID * TILE;

    float cntp[VEC] = {0.f, 0.f, 0.f, 0.f};
    float sall[VEC] = {0.f, 0.f, 0.f, 0.f};
    float spos[VEC] = {0.f, 0.f, 0.f, 0.f};
    float spe[VEC]  = {0.f, 0.f, 0.f, 0.f};
    float sne[VEC]  = {0.f, 0.f, 0.f, 0.f};

    const int tid = threadIdx.x;
    const size_t base0 = (size_t)blockIdx.x * TILE + (size_t)tid * VEC;

    float4 pc[UNROLL], tc[UNROLL];
    #pragma unroll
    for (int u = 0; u < UNROLL; ++u) {
        pc[u] = *reinterpret_cast<const float4*>(pred + base0 + (size_t)u * (BLOCK * VEC));
        tc[u] = *reinterpret_cast<const float4*>(tgt  + base0 + (size_t)u * (BLOCK * VEC));
    }

    #pragma unroll
    for (int it = 0; it < ITERS; ++it) {
        float4 pn[UNROLL], tn[UNROLL];
        if (it + 1 < ITERS) {
            const size_t nb = base0 + (size_t)(it + 1) * STRIDE;
            #pragma unroll
            for (int u = 0; u < UNROLL; ++u) {
                pn[u] = *reinterpret_cast<const float4*>(pred + nb + (size_t)u * (BLOCK * VEC));
                tn[u] = *reinterpret_cast<const float4*>(tgt  + nb + (size_t)u * (BLOCK * VEC));
            }
        }
        #pragma unroll
        for (int u = 0; u < UNROLL; ++u) {
            const float px[4] = {pc[u].x, pc[u].y, pc[u].z, pc[u].w};
            const float tx[4] = {tc[u].x, tc[u].y, tc[u].z, tc[u].w};
            #pragma unroll
            for (int j = 0; j < VEC; ++j) {
                const float x  = px[j];
                const float tv = tx[j];
                const float e  = __expf(-fabsf(x));
                const float sp_ = __logf(1.f + e);            // softplus(-|x|)
                const float bce = sp_ + fmaxf(x, 0.f) - x * tv;
                const float bpos = (x >  LN9) ? bce : 0.f;    // easy positive
                const float bneg = (x < -LN9) ? bce : 0.f;    // easy negative
                cntp[j] += tv;
                sall[j] += bce;
                spos[j]  = fmaf(tv, bce,   spos[j]);
                spe[j]   = fmaf(tv, bpos,  spe[j]);           // t * easy-pos
                sne[j]   = fmaf(-tv, bneg, sne[j] + bneg);    // (1-t) * easy-neg
            }
        }
        if (it + 1 < ITERS) {
            #pragma unroll
            for (int u = 0; u < UNROLL; ++u) { pc[u] = pn[u]; tc[u] = tn[u]; }
        }
    }

    __shared__ float lacc[C_N * 5];
    if (tid < C_N * 5) lacc[tid] = 0.f;
    __syncthreads();
    const int c0 = (tid * VEC) % C_N;          // constant classes per thread
    #pragma unroll
    for (int j = 0; j < VEC; ++j) {
        float* a = &lacc[(c0 + j) * 5];
        atomicAdd(a + 0, cntp[j]);
        atomicAdd(a + 1, sall[j]);
        atomicAdd(a + 2, spos[j]);
        atomicAdd(a + 3, spe[j]);
        atomicAdd(a + 4, sne[j]);
    }
    __syncthreads();
    if (tid < C_N * 5)
        atomicAdd(&gacc[(blockIdx.x % NREP) * (C_N * 5) + tid], lacc[tid]);
}

__global__ void bdl_final(const float* __restrict__ gacc, float* __restrict__ out)
{
    __shared__ float acc[C_N * 5];
    const int tid = threadIdx.x;
    if (tid < C_N * 5) {
        float s = 0.f;
        #pragma unroll
        for (int r = 0; r < NREP; ++r) s += gacc[r * (C_N * 5) + tid];
        acc[tid] = s;
    }
    __syncthreads();
    if (tid == 0) {
        const float Bf  = (float)B_N;
        const float bal = 0.5f * Bf;               // PROP * batch
        float tot = 0.f;
        for (int c = 0; c < C_N; ++c) {
            const float cntp = acc[c * 5 + 0];
            const float sall = acc[c * 5 + 1];
            const float sp   = acc[c * 5 + 2];
            const float spe  = acc[c * 5 + 3];
            const float sne  = acc[c * 5 + 4];
            const float sn   = sall - sp;
            const bool posmaj = (cntp >= bal);     // pos_gt; else neg_gt
            const float nmaj = posmaj ? cntp : (Bf - cntp);
            const float nmin = Bf - nmaj;
            const float smaj = posmaj ? (sp - spe) : (sn - sne);
            const float smin = posmaj ? sn : sp;
            const float wmaj = bal / fmaxf(nmaj, 1.f);
            const float wmin = (nmin > 0.f) ? ((Bf - bal) / fmaxf(nmin, 1.f)) : 1.f;
            tot += smaj * wmaj + smin * wmin;
        }
        out[0] = tot / (Bf * (float)C_N);
    }
}

extern "C" void kernel_launch(void* const* d_in, const int* in_sizes, int n_in,
                              void* d_out, int out_size, void* d_ws, size_t ws_size,
                              hipStream_t stream) {
    const float* pred = (const float*)d_in[0];
    const float* tgt  = (const float*)d_in[1];
    float* gacc = (float*)d_ws;                       // NREP*200 floats = 25.6 KB
    hipMemsetAsync(gacc, 0, NREP * C_N * 5 * sizeof(float), stream);
    bdl_accum<<<GRID, BLOCK, 0, stream>>>(pred, tgt, gacc);
    bdl_final<<<1, 256, 0, stream>>>(gacc, (float*)d_out);
}

// Round 5
// 82.247 us; speedup vs baseline: 1.2646x; 1.2646x over previous
//
#include <hip/hip_runtime.h>
#include <math.h>

#define B_N 524288
#define C_N 40
constexpr int BLOCK  = 320;   // 5 waves; 320*4 = 1280 floats = 32 rows of C=40
constexpr int VEC    = 4;
constexpr int UNROLL = 2;     // 2 float4-pairs batched per iteration
constexpr int GRID   = 1536;  // 6 blocks/CU x 5 waves = 30/32 waves, SINGLE round
constexpr int NREP   = 32;    // accumulator replicas to spread atomic contention

// Fused single pass. Key layout facts:
//  - tile = BLOCK*VEC*UNROLL = 2560 == 0 (mod 40)  -> per-thread classes fixed
//  - total/tile = 8192 exactly -> tile-granular guard, no partial tiles
//  - GRID=1536: all blocks co-resident (one dispatch round, no low-occ tail)
__global__ __launch_bounds__(BLOCK) void bdl_accum(
    const float* __restrict__ pred, const float* __restrict__ tgt,
    float* __restrict__ gacc)
{
    constexpr float LN9 = 2.1972245773362196f;
    constexpr size_t TILE   = (size_t)BLOCK * VEC * UNROLL;  // 2560
    constexpr size_t STRIDE = (size_t)GRID * TILE;
    constexpr size_t TOTAL  = (size_t)B_N * C_N;

    float cntp[VEC] = {0.f, 0.f, 0.f, 0.f};
    float sall[VEC] = {0.f, 0.f, 0.f, 0.f};
    float spos[VEC] = {0.f, 0.f, 0.f, 0.f};
    float spe[VEC]  = {0.f, 0.f, 0.f, 0.f};
    float sne[VEC]  = {0.f, 0.f, 0.f, 0.f};

    const int tid = threadIdx.x;

    for (size_t base = (size_t)blockIdx.x * TILE + (size_t)tid * VEC;
         base < TOTAL; base += STRIDE) {
        float4 p[UNROLL], t[UNROLL];
        #pragma unroll
        for (int u = 0; u < UNROLL; ++u) {
            p[u] = *reinterpret_cast<const float4*>(pred + base + (size_t)u * (BLOCK * VEC));
            t[u] = *reinterpret_cast<const float4*>(tgt  + base + (size_t)u * (BLOCK * VEC));
        }
        #pragma unroll
        for (int u = 0; u < UNROLL; ++u) {
            const float px[4] = {p[u].x, p[u].y, p[u].z, p[u].w};
            const float tx[4] = {t[u].x, t[u].y, t[u].z, t[u].w};
            #pragma unroll
            for (int j = 0; j < VEC; ++j) {
                const float x  = px[j];
                const float tv = tx[j];
                const float e  = __expf(-fabsf(x));
                const float sp_ = __logf(1.f + e);            // softplus(-|x|)
                const float bce = sp_ + fmaxf(x, 0.f) - x * tv;
                const float bpos = (x >  LN9) ? bce : 0.f;    // easy positive
                const float bneg = (x < -LN9) ? bce : 0.f;    // easy negative
                cntp[j] += tv;
                sall[j] += bce;
                spos[j]  = fmaf(tv, bce,   spos[j]);
                spe[j]   = fmaf(tv, bpos,  spe[j]);           // t * easy-pos
                sne[j]   = fmaf(-tv, bneg, sne[j] + bneg);    // (1-t) * easy-neg
            }
        }
    }

    __shared__ float lacc[C_N * 5];
    if (tid < C_N * 5) lacc[tid] = 0.f;
    __syncthreads();
    const int c0 = (tid * VEC) % C_N;          // constant classes per thread
    #pragma unroll
    for (int j = 0; j < VEC; ++j) {
        float* a = &lacc[(c0 + j) * 5];
        atomicAdd(a + 0, cntp[j]);
        atomicAdd(a + 1, sall[j]);
        atomicAdd(a + 2, spos[j]);
        atomicAdd(a + 3, spe[j]);
        atomicAdd(a + 4, sne[j]);
    }
    __syncthreads();
    if (tid < C_N * 5)
        atomicAdd(&gacc[(blockIdx.x % NREP) * (C_N * 5) + tid], lacc[tid]);
}

__global__ void bdl_final(const float* __restrict__ gacc, float* __restrict__ out)
{
    __shared__ float acc[C_N * 5];
    const int tid = threadIdx.x;
    if (tid < C_N * 5) {
        float s = 0.f;
        #pragma unroll
        for (int r = 0; r < NREP; ++r) s += gacc[r * (C_N * 5) + tid];
        acc[tid] = s;
    }
    __syncthreads();
    if (tid == 0) {
        const float Bf  = (float)B_N;
        const float bal = 0.5f * Bf;               // PROP * batch
        float tot = 0.f;
        for (int c = 0; c < C_N; ++c) {
            const float cntp = acc[c * 5 + 0];
            const float sall = acc[c * 5 + 1];
            const float sp   = acc[c * 5 + 2];
            const float spe  = acc[c * 5 + 3];
            const float sne  = acc[c * 5 + 4];
            const float sn   = sall - sp;
            const bool posmaj = (cntp >= bal);     // pos_gt; else neg_gt
            const float nmaj = posmaj ? cntp : (Bf - cntp);
            const float nmin = Bf - nmaj;
            const float smaj = posmaj ? (sp - spe) : (sn - sne);
            const float smin = posmaj ? sn : sp;
            const float wmaj = bal / fmaxf(nmaj, 1.f);
            const float wmin = (nmin > 0.f) ? ((Bf - bal) / fmaxf(nmin, 1.f)) : 1.f;
            tot += smaj * wmaj + smin * wmin;
        }
        out[0] = tot / (Bf * (float)C_N);
    }
}

extern "C" void kernel_launch(void* const* d_in, const int* in_sizes, int n_in,
                              void* d_out, int out_size, void* d_ws, size_t ws_size,
                              hipStream_t stream) {
    const float* pred = (const float*)d_in[0];
    const float* tgt  = (const float*)d_in[1];
    float* gacc = (float*)d_ws;                       // NREP*200 floats = 25.6 KB
    hipMemsetAsync(gacc, 0, NREP * C_N * 5 * sizeof(float), stream);
    bdl_accum<<<GRID, BLOCK, 0, stream>>>(pred, tgt, gacc);
    bdl_final<<<1, 256, 0, stream>>>(gacc, (float*)d_out);
}

// Round 6
// 66.824 us; speedup vs baseline: 1.5565x; 1.2308x over previous
//
#include <hip/hip_runtime.h>
#include <math.h>

#define B_N 524288
#define C_N 40
constexpr int BLOCK  = 320;   // 5 waves; 320*4 = 1280 floats = 32 rows of C=40
constexpr int VEC    = 4;
constexpr int UNROLL = 4;     // 8 float4 loads batched per iteration
constexpr int GRID   = 1024;  // 1024*5120*4 == 524288*40 exactly (4 iters, no guard)
constexpr int ITERS  = 4;
constexpr int NREP   = 32;    // accumulator replicas to spread atomic contention

// R3 geometry + forced memory-level parallelism:
//  - all 8 loads issued (p/t interleaved), then sched_barrier(0) pins them
//    BEFORE any consumption -> ~8KB in flight per wave instead of ~1.5KB.
//  - __launch_bounds__(320,4) raises VGPR cap so the batch can stay live.
// Tile = 5120 == 0 mod 40 -> per-thread classes invariant across iterations.
__global__ __launch_bounds__(BLOCK, 4) void bdl_accum(
    const float* __restrict__ pred, const float* __restrict__ tgt,
    float* __restrict__ gacc)
{
    constexpr float LN9 = 2.1972245773362196f;
    constexpr size_t TILE   = (size_t)BLOCK * VEC * UNROLL;  // 5120
    constexpr size_t STRIDE = (size_t)GRID * TILE;
    constexpr int    W      = BLOCK * VEC;                   // 1280

    float cntp[VEC] = {0.f, 0.f, 0.f, 0.f};
    float sall[VEC] = {0.f, 0.f, 0.f, 0.f};
    float spos[VEC] = {0.f, 0.f, 0.f, 0.f};
    float spe[VEC]  = {0.f, 0.f, 0.f, 0.f};
    float sne[VEC]  = {0.f, 0.f, 0.f, 0.f};

    const int tid = threadIdx.x;
    size_t base = (size_t)blockIdx.x * TILE + (size_t)tid * VEC;

    #pragma unroll 1
    for (int it = 0; it < ITERS; ++it, base += STRIDE) {
        // ---- issue phase: 8 independent dwordx4 loads, interleaved p/t ----
        const float4 p0 = *reinterpret_cast<const float4*>(pred + base + 0 * W);
        const float4 t0 = *reinterpret_cast<const float4*>(tgt  + base + 0 * W);
        const float4 p1 = *reinterpret_cast<const float4*>(pred + base + 1 * W);
        const float4 t1 = *reinterpret_cast<const float4*>(tgt  + base + 1 * W);
        const float4 p2 = *reinterpret_cast<const float4*>(pred + base + 2 * W);
        const float4 t2 = *reinterpret_cast<const float4*>(tgt  + base + 2 * W);
        const float4 p3 = *reinterpret_cast<const float4*>(pred + base + 3 * W);
        const float4 t3 = *reinterpret_cast<const float4*>(tgt  + base + 3 * W);
        __builtin_amdgcn_sched_barrier(0);   // loads may not sink past this

        const float4 pu[UNROLL] = {p0, p1, p2, p3};
        const float4 tu[UNROLL] = {t0, t1, t2, t3};
        #pragma unroll
        for (int u = 0; u < UNROLL; ++u) {
            const float px[4] = {pu[u].x, pu[u].y, pu[u].z, pu[u].w};
            const float tx[4] = {tu[u].x, tu[u].y, tu[u].z, tu[u].w};
            #pragma unroll
            for (int j = 0; j < VEC; ++j) {
                const float x  = px[j];
                const float tv = tx[j];
                const float e  = __expf(-fabsf(x));
                const float sp_ = __logf(1.f + e);            // softplus(-|x|)
                const float bce = sp_ + fmaxf(x, 0.f) - x * tv;
                const float bpos = (x >  LN9) ? bce : 0.f;    // easy positive
                const float bneg = (x < -LN9) ? bce : 0.f;    // easy negative
                cntp[j] += tv;
                sall[j] += bce;
                spos[j]  = fmaf(tv, bce,   spos[j]);
                spe[j]   = fmaf(tv, bpos,  spe[j]);           // t * easy-pos
                sne[j]   = fmaf(-tv, bneg, sne[j] + bneg);    // (1-t) * easy-neg
            }
        }
    }

    __shared__ float lacc[C_N * 5];
    if (tid < C_N * 5) lacc[tid] = 0.f;
    __syncthreads();
    const int c0 = (tid * VEC) % C_N;          // constant classes per thread
    #pragma unroll
    for (int j = 0; j < VEC; ++j) {
        float* a = &lacc[(c0 + j) * 5];
        atomicAdd(a + 0, cntp[j]);
        atomicAdd(a + 1, sall[j]);
        atomicAdd(a + 2, spos[j]);
        atomicAdd(a + 3, spe[j]);
        atomicAdd(a + 4, sne[j]);
    }
    __syncthreads();
    if (tid < C_N * 5)
        atomicAdd(&gacc[(blockIdx.x % NREP) * (C_N * 5) + tid], lacc[tid]);
}

__global__ void bdl_final(const float* __restrict__ gacc, float* __restrict__ out)
{
    __shared__ float acc[C_N * 5];
    const int tid = threadIdx.x;
    if (tid < C_N * 5) {
        float s = 0.f;
        #pragma unroll
        for (int r = 0; r < NREP; ++r) s += gacc[r * (C_N * 5) + tid];
        acc[tid] = s;
    }
    __syncthreads();
    if (tid == 0) {
        const float Bf  = (float)B_N;
        const float bal = 0.5f * Bf;               // PROP * batch
        float tot = 0.f;
        for (int c = 0; c < C_N; ++c) {
            const float cntp = acc[c * 5 + 0];
            const float sall = acc[c * 5 + 1];
            const float sp   = acc[c * 5 + 2];
            const float spe  = acc[c * 5 + 3];
            const float sne  = acc[c * 5 + 4];
            const float sn   = sall - sp;
            const bool posmaj = (cntp >= bal);     // pos_gt; else neg_gt
            const float nmaj = posmaj ? cntp : (Bf - cntp);
            const float nmin = Bf - nmaj;
            const float smaj = posmaj ? (sp - spe) : (sn - sne);
            const float smin = posmaj ? sn : sp;
            const float wmaj = bal / fmaxf(nmaj, 1.f);
            const float wmin = (nmin > 0.f) ? ((Bf - bal) / fmaxf(nmin, 1.f)) : 1.f;
            tot += smaj * wmaj + smin * wmin;
        }
        out[0] = tot / (Bf * (float)C_N);
    }
}

extern "C" void kernel_launch(void* const* d_in, const int* in_sizes, int n_in,
                              void* d_out, int out_size, void* d_ws, size_t ws_size,
                              hipStream_t stream) {
    const float* pred = (const float*)d_in[0];
    const float* tgt  = (const float*)d_in[1];
    float* gacc = (float*)d_ws;                       // NREP*200 floats = 25.6 KB
    hipMemsetAsync(gacc, 0, NREP * C_N * 5 * sizeof(float), stream);
    bdl_accum<<<GRID, BLOCK, 0, stream>>>(pred, tgt, gacc);
    bdl_final<<<1, 256, 0, stream>>>(gacc, (float*)d_out);
}

// Round 9
// 64.349 us; speedup vs baseline: 1.6163x; 1.0385x over previous
//
#include <hip/hip_runtime.h>
#include <math.h>

#define B_N 524288
#define C_N 40
constexpr int BLOCK  = 320;   // 5 waves; 320*4 = 1280 floats = 32 rows of C=40
constexpr int VEC    = 4;
constexpr int UNROLL = 4;     // 4 float4-pairs per iteration (R3 geometry)
constexpr int GRID   = 1024;  // exactly 4 iterations/block, perfectly balanced
constexpr int NREP   = 32;    // accumulator replicas to spread atomic contention

typedef float f32x4 __attribute__((ext_vector_type(4)));

// Nontemporal streaming load: global_load_dwordx4 with nt hint (bypass L1
// allocation). Pure cache hint -> semantics identical to a plain load.
__device__ __forceinline__ f32x4 ldnt(const float* p) {
    return __builtin_nontemporal_load(reinterpret_cast<const f32x4*>(p));
}

// R3 structure (78us champion), loads swapped to nontemporal. Tile = 5120
// == 0 mod 40 -> per-thread classes invariant across unroll slots and iters.
__global__ __launch_bounds__(BLOCK) void bdl_accum(
    const float* __restrict__ pred, const float* __restrict__ tgt,
    float* __restrict__ gacc)
{
    constexpr float  LN9    = 2.1972245773362196f;
    constexpr size_t TILE   = (size_t)BLOCK * VEC * UNROLL;  // 5120
    constexpr size_t STRIDE = (size_t)GRID * TILE;
    constexpr size_t TOTAL  = (size_t)B_N * C_N;
    constexpr int    W      = BLOCK * VEC;                   // 1280

    float cntp[VEC] = {0.f,0.f,0.f,0.f};
    float sall[VEC] = {0.f,0.f,0.f,0.f};
    float spos[VEC] = {0.f,0.f,0.f,0.f};
    float spe[VEC]  = {0.f,0.f,0.f,0.f};
    float sne[VEC]  = {0.f,0.f,0.f,0.f};

    const int tid = threadIdx.x;

    for (size_t base = (size_t)blockIdx.x * TILE + (size_t)tid * VEC;
         base < TOTAL; base += STRIDE) {
        f32x4 p[UNROLL], t[UNROLL];
        #pragma unroll
        for (int u = 0; u < UNROLL; ++u) {
            p[u] = ldnt(pred + base + (size_t)u * W);
            t[u] = ldnt(tgt  + base + (size_t)u * W);
        }
        #pragma unroll
        for (int u = 0; u < UNROLL; ++u) {
            #pragma unroll
            for (int j = 0; j < VEC; ++j) {
                const float x  = p[u][j];
                const float tv = t[u][j];
                const float e  = __expf(-fabsf(x));
                const float sp_ = __logf(1.f + e);            // softplus(-|x|)
                const float bce = sp_ + fmaxf(x, 0.f) - x * tv;
                const float bpos = (x >  LN9) ? bce : 0.f;    // easy positive
                const float bneg = (x < -LN9) ? bce : 0.f;    // easy negative
                cntp[j] += tv;
                sall[j] += bce;
                spos[j]  = fmaf(tv, bce,   spos[j]);
                spe[j]   = fmaf(tv, bpos,  spe[j]);           // t * easy-pos
                sne[j]   = fmaf(-tv, bneg, sne[j] + bneg);    // (1-t) * easy-neg
            }
        }
    }

    __shared__ float lacc[C_N * 5];
    if (tid < C_N * 5) lacc[tid] = 0.f;
    __syncthreads();
    const int c0 = (tid * VEC) % C_N;          // constant classes per thread
    #pragma unroll
    for (int j = 0; j < VEC; ++j) {
        float* a = &lacc[(c0 + j) * 5];
        atomicAdd(a + 0, cntp[j]);
        atomicAdd(a + 1, sall[j]);
        atomicAdd(a + 2, spos[j]);
        atomicAdd(a + 3, spe[j]);
        atomicAdd(a + 4, sne[j]);
    }
    __syncthreads();
    if (tid < C_N * 5)
        atomicAdd(&gacc[(blockIdx.x % NREP) * (C_N * 5) + tid], lacc[tid]);
}

__global__ void bdl_final(const float* __restrict__ gacc, float* __restrict__ out)
{
    __shared__ float acc[C_N * 5];
    const int tid = threadIdx.x;
    if (tid < C_N * 5) {
        float s = 0.f;
        #pragma unroll
        for (int r = 0; r < NREP; ++r) s += gacc[r * (C_N * 5) + tid];
        acc[tid] = s;
    }
    __syncthreads();
    if (tid == 0) {
        const float Bf  = (float)B_N;
        const float bal = 0.5f * Bf;               // PROP * batch
        float tot = 0.f;
        for (int c = 0; c < C_N; ++c) {
            const float cntp = acc[c * 5 + 0];
            const float sall = acc[c * 5 + 1];
            const float sp   = acc[c * 5 + 2];
            const float spe  = acc[c * 5 + 3];
            const float sne  = acc[c * 5 + 4];
            const float sn   = sall - sp;
            const bool posmaj = (cntp >= bal);     // pos_gt; else neg_gt
            const float nmaj = posmaj ? cntp : (Bf - cntp);
            const float nmin = Bf - nmaj;
            const float smaj = posmaj ? (sp - spe) : (sn - sne);
            const float smin = posmaj ? sn : sp;
            const float wmaj = bal / fmaxf(nmaj, 1.f);
            const float wmin = (nmin > 0.f) ? ((Bf - bal) / fmaxf(nmin, 1.f)) : 1.f;
            tot += smaj * wmaj + smin * wmin;
        }
        out[0] = tot / (Bf * (float)C_N);
    }
}

extern "C" void kernel_launch(void* const* d_in, const int* in_sizes, int n_in,
                              void* d_out, int out_size, void* d_ws, size_t ws_size,
                              hipStream_t stream) {
    const float* pred = (const float*)d_in[0];
    const float* tgt  = (const float*)d_in[1];
    float* gacc = (float*)d_ws;                       // NREP*200 floats = 25.6 KB
    hipMemsetAsync(gacc, 0, NREP * C_N * 5 * sizeof(float), stream);
    bdl_accum<<<GRID, BLOCK, 0, stream>>>(pred, tgt, gacc);
    bdl_final<<<1, 256, 0, stream>>>(gacc, (float*)d_out);
}